// Round 5
// baseline (261.511 us; speedup 1.0000x reference)
//
#include <hip/hip_runtime.h>
#include <cstddef>

// Problem constants (match reference)
#define B_   256
#define T_   2048
#define DIM_ 64
#define NC_  16              // chunks per row
#define CS_  (T_ / NC_)      // 128 steps per chunk
#define SG_  16              // step-subgroups per scan block
#define SPS_ (CS_ / SG_)     // 8 steps per subgroup -> 8 float4 regs/thread
// THETA=0.1, MU=0, SIGMA=1 ; sigma/sqrt(2*theta) = sqrt(5)
#define OU_SCALE 2.2360679774997896f

// native clang vector for __builtin_nontemporal_store (HIP float4 is a class
// type the builtin rejects; this has identical 16B layout)
typedef float nfloat4 __attribute__((ext_vector_type(4)));

// delta coefficients for step t of row b:
//  x: brownian-increment std (0 if invalid), y: OU-increment std * sqrt(5)
__device__ __forceinline__ float2 delta_pair(const float* __restrict__ tsb, int t) {
    float tk = tsb[t];
    float tp = (t == 0) ? 0.0f : tsb[t - 1];
    float dt = tk - tp;
    float db  = sqrtf(dt);
    // exp(2θ tk) - exp(2θ tp) = exp(2θ tp) * expm1(2θ dt)
    float dou = sqrtf(expf(0.2f * tp) * expm1f(0.2f * dt));
    float cb = (db  <= 0.0f) ? 0.0f : db;
    float co = (dou <= 0.0f) ? 0.0f : dou * OU_SCALE;
    return make_float2(cb, co);
}

// ---------------------------------------------------------------------------
// Kernel 1: per-row chunk partials + in-block exclusive prefix -> BASE rows.
// One block per row b (1024 threads = 16 waves). Wave w reduces chunk w
// (float4 coalesced, shfl combine); after one barrier, thread (c,l) sums
// partials k<c and writes the exclusive BASE to out[b, c*CS, l] — the head
// row of chunk c's own output region. Replaces the round-2 partial_kernel
// + prefix_kernel pair (the latter was latency-bound plus a launch gap).
__global__ __launch_bounds__(1024) void base_kernel(
        const float* __restrict__ ts,
        const float* __restrict__ noise,
        float* __restrict__ out)
{
    __shared__ float2 dlt[T_];          // 16 KB: delta pair per step
    __shared__ float  par[NC_][DIM_];   // 4 KB : chunk partials

    const int b   = blockIdx.x;
    const int tid = threadIdx.x;
    const int w   = tid >> 6;           // wave id = chunk id
    const int l   = tid & 63;

    // Stage 0: all per-step delta pairs for row b (2 steps/thread)
    const float* tsb = ts + (size_t)b * T_;
    for (int t = tid; t < T_; t += 1024)
        dlt[t] = delta_pair(tsb, t);
    __syncthreads();

    const size_t rowbase = (size_t)b * T_ * DIM_;

    // Phase A: wave w -> weighted partial of chunk w (chunk 15's partial is
    // never needed for an exclusive prefix; wave 15 idles to the barrier).
    if (w != NC_ - 1) {
        const int  g   = l >> 4;            // step subgroup 0..3
        const int  dq  = (l & 15) << 2;     // dim quad base (within one half)
        const bool ouA = (dq >= DIM_ / 2);
        const int  tb  = w * CS_;
        float4 a = make_float4(0.f, 0.f, 0.f, 0.f);
#pragma unroll 8
        for (int i = 0; i < CS_ / 4; ++i) {
            const int t = tb + (i << 2) + g;
            const float4 v = *(const float4*)(noise + rowbase + (size_t)t * DIM_ + dq);
            const float2 d2 = dlt[t];
            const float delta = ouA ? d2.y : d2.x;
            a.x = fmaf(delta, v.x, a.x);
            a.y = fmaf(delta, v.y, a.y);
            a.z = fmaf(delta, v.z, a.z);
            a.w = fmaf(delta, v.w, a.w);
        }
        a.x += __shfl_xor(a.x, 16); a.y += __shfl_xor(a.y, 16);
        a.z += __shfl_xor(a.z, 16); a.w += __shfl_xor(a.w, 16);
        a.x += __shfl_xor(a.x, 32); a.y += __shfl_xor(a.y, 32);
        a.z += __shfl_xor(a.z, 32); a.w += __shfl_xor(a.w, 32);
        if (l < 16) *(float4*)&par[w][l << 2] = a;
    }
    __syncthreads();

    // Exclusive prefix: thread tid = (c,l) covers all 16x64 outputs exactly.
    // par[k][l] reads: 64 lanes hit banks 0..31 twice -> 2-way (free).
    const int c = w;                    // chunk handled by this thread
    float acc = 0.0f;
    for (int k = 0; k < c; ++k) acc += par[k][l];
    out[rowbase + (size_t)c * CS_ * DIM_ + l] = acc;   // base stash, re-read by K2
}

// ---------------------------------------------------------------------------
// Kernel 2: block (b,c) reads its base from ITS OWN head row (written by K1,
// visible via kernel boundary; no cross-block ordering needed), re-reads its
// noise chunk (L3-hot from K1), scans, normalizes, nontemporal float4 stores
// (out is never re-read -> don't evict noise from L2/L3).
__global__ __launch_bounds__(256) void scan_kernel(
        const float* __restrict__ ts,
        const float* __restrict__ noise,
        float* __restrict__ out)
{
    __shared__ float4 cof[CS_];        // {d_bm, d_ou*sqrt5, f_bm, f_ou} 2 KB
    __shared__ float4 red[SG_][16];    // 4 KB

    const int v   = blockIdx.x;
    const int b   = v >> 4;
    const int c   = v & (NC_ - 1);
    const int tid = threadIdx.x;
    const int sg  = tid >> 4;
    const int qi  = tid & 15;
    const int q   = qi << 2;
    const int t0  = c * CS_;

    const size_t rowbase = (size_t)b * T_ * DIM_;
    const float* np = noise + rowbase + (size_t)(t0 + sg * SPS_) * DIM_ + q;
    float4 r[SPS_];
#pragma unroll
    for (int i = 0; i < SPS_; ++i)
        r[i] = *(const float4*)(np + (size_t)i * DIM_);

    // cross-chunk base from this block's own stash slot (written by K1)
    float4 base = *(const float4*)(out + rowbase + (size_t)t0 * DIM_ + q);

    const float* tsb = ts + (size_t)b * T_;
    if (tid < CS_) {
        int t = t0 + tid;
        float2 d  = delta_pair(tsb, t);
        float tk  = tsb[t];
        float fb  = 1.0f / (sqrtf(tk) + 1e-8f);
        float em  = expf(-0.1f * tk);                      // exp(-θ t)
        float fo  = em / (sqrtf(-expm1f(-0.2f * tk) * 5.0f) + 1e-8f);
        cof[tid] = make_float4(d.x, d.y, fb, fo);
    }
    __syncthreads();   // also orders every thread's base-read before any store

    // weight in place, accumulate subgroup partial
    const bool ou = q >= (DIM_ / 2);
    float4 s = make_float4(0.f, 0.f, 0.f, 0.f);
#pragma unroll
    for (int i = 0; i < SPS_; ++i) {
        float4 cc = cof[sg * SPS_ + i];
        float d = ou ? cc.y : cc.x;
        r[i].x *= d; r[i].y *= d; r[i].z *= d; r[i].w *= d;
        s.x += r[i].x; s.y += r[i].y; s.z += r[i].z; s.w += r[i].w;
    }
    red[sg][qi] = s;
    __syncthreads();

    // exclusive prefix over earlier subgroups of this chunk
    float4 acc = base;
    for (int k = 0; k < sg; ++k) {
        float4 p = red[k][qi];
        acc.x += p.x; acc.y += p.y; acc.z += p.z; acc.w += p.w;
    }

    // replay from registers, normalize, nontemporal float4 store
    float* op = out + rowbase + (size_t)(t0 + sg * SPS_) * DIM_ + q;
#pragma unroll
    for (int i = 0; i < SPS_; ++i) {
        float4 cc = cof[sg * SPS_ + i];
        float f = ou ? cc.w : cc.z;
        acc.x += r[i].x; acc.y += r[i].y; acc.z += r[i].z; acc.w += r[i].w;
        nfloat4 o = { acc.x * f, acc.y * f, acc.z * f, acc.w * f };
        __builtin_nontemporal_store(o, (nfloat4*)(op + (size_t)i * DIM_));
    }
}

// ---------------------------------------------------------------------------
extern "C" void kernel_launch(void* const* d_in, const int* in_sizes, int n_in,
                              void* d_out, int out_size, void* d_ws, size_t ws_size,
                              hipStream_t stream) {
    const float* ts    = (const float*)d_in[0];   // [B,T,1] fp32
    const float* noise = (const float*)d_in[1];   // [B,T,DIM] fp32
    float* out = (float*)d_out;                   // [B,T,DIM] fp32
    // d_ws deliberately untouched (workspace poison-fill). Bases live in out.
    (void)d_ws; (void)ws_size; (void)in_sizes; (void)n_in; (void)out_size;

    base_kernel<<<B_,       1024, 0, stream>>>(ts, noise, out);
    scan_kernel<<<B_ * NC_, 256,  0, stream>>>(ts, noise, out);
}